// Round 3
// baseline (496.371 us; speedup 1.0000x reference)
//
#include <hip/hip_runtime.h>

// NestLinearQuantizer: out = quant(x) @ dequant(packed)^T + bias
// Factored to int8 GEMM:  out[t,o] = as*scale[o]*(dot_i8[t,o] - zp[o]*rowsum[t]) + bias[o]
// where q[o,i] = max(hi_nibble*16 + (packed_low - 144), -128)  (exact int8),
// xi8 = clip(rint(x/as), -128, 127).

typedef int v4i __attribute__((ext_vector_type(4)));

#define TOKENS 256
#define INF 8192
#define OUTF 8192

// ---------------- Kernel 1: quantize activations to int8 + per-token rowsum --------
__global__ __launch_bounds__(256) void quant_x_kernel(
    const float* __restrict__ x, const float* __restrict__ act_scale,
    signed char* __restrict__ xi8, int* __restrict__ rowsum)
{
    const int t = blockIdx.x;
    const int j = threadIdx.x;
    const float s = act_scale[0];
    const float4* xrow = (const float4*)(x + (size_t)t * INF);
    int* qrow = (int*)(xi8 + (size_t)t * INF);
    int lsum = 0;
#pragma unroll
    for (int c = 0; c < 8; ++c) {
        float4 v = xrow[j + c * 256];
        // jnp.round == round-half-to-even == rintf under default rounding mode
        int q0 = (int)rintf(v.x / s); q0 = q0 < -128 ? -128 : (q0 > 127 ? 127 : q0);
        int q1 = (int)rintf(v.y / s); q1 = q1 < -128 ? -128 : (q1 > 127 ? 127 : q1);
        int q2 = (int)rintf(v.z / s); q2 = q2 < -128 ? -128 : (q2 > 127 ? 127 : q2);
        int q3 = (int)rintf(v.w / s); q3 = q3 < -128 ? -128 : (q3 > 127 ? 127 : q3);
        qrow[j + c * 256] = (q0 & 255) | ((q1 & 255) << 8) | ((q2 & 255) << 16) | ((q3 & 255) << 24);
        lsum += q0 + q1 + q2 + q3;
    }
#pragma unroll
    for (int off = 32; off > 0; off >>= 1) lsum += __shfl_down(lsum, off, 64);
    __shared__ int wsum[4];
    if ((j & 63) == 0) wsum[j >> 6] = lsum;
    __syncthreads();
    if (j == 0) rowsum[t] = wsum[0] + wsum[1] + wsum[2] + wsum[3];
}

// ---------------- Kernel 2: fused unpack + int8 MFMA GEMM + epilogue ----------------
// BM=256 (all tokens), BN=32 cols/block -> 256 blocks (1/CU). K-step 64.
// 8 waves: wave w owns rows [w*32, w*32+32) x all 32 cols = 2x2 tiles of 16x16x64.
// B staged via LDS (unpack once, shared by 8 waves); A loaded global->VGPR (L2-hot).
// Barriers are raw s_barrier with lgkmcnt(0) only -- global prefetch loads stay
// in flight across barriers (T4), consumed with counted vmcnt by the compiler.
__global__ __launch_bounds__(512) void gemm_kernel(
    const signed char* __restrict__ xi8, const int* __restrict__ rowsum,
    const int* __restrict__ packed_high, const int* __restrict__ packed_low,
    const float* __restrict__ scale, const float* __restrict__ zero_point,
    const float* __restrict__ bias, const float* __restrict__ act_scale,
    float* __restrict__ out)
{
    // [buf][kgroup][o][16 bytes of k]  -- B fragment reads are lane-linear (2-way, free)
    __shared__ __align__(16) signed char Blds[2][4][32][16];

    const int tid  = threadIdx.x;
    const int lane = tid & 63;
    const int w    = tid >> 6;
    const int n0   = blockIdx.x * 32;

    // --- B staging mapping: thread -> (col so, 4 consecutive k at si) ---
    const int so = tid >> 4;          // 0..31
    const int si = (tid & 15) << 2;   // 0,4,...,60
    const int* pl_ptr = packed_low  + (size_t)(n0 + so) * INF       + si;
    const int* ph_ptr = packed_high + (size_t)(n0 + so) * (INF / 2) + (si >> 1);

    // --- A fragment pointer: lane holds row w*32 + (lane&15), k = (lane>>4)*16 + j ---
    const signed char* a_ptr = xi8 + (size_t)((w << 5) + (lane & 15)) * INF + ((lane >> 4) << 4);

    v4i acc00 = {0, 0, 0, 0}, acc01 = {0, 0, 0, 0}, acc10 = {0, 0, 0, 0}, acc11 = {0, 0, 0, 0};

    // prologue loads for tile 0
    int4 pl = *(const int4*)pl_ptr;
    int2 ph = *(const int2*)ph_ptr;
    v4i  a0 = *(const v4i*)a_ptr;
    v4i  a1 = *(const v4i*)(a_ptr + 16 * INF);

#define PROCESS_TILE(T)                                                                   \
    {                                                                                     \
        /* unpack:  q = max(nib*16 + pl - 144, -128) */                                   \
        int q0 = (ph.x & 0xF0)        + pl.x - 144; if (q0 < -128) q0 = -128;             \
        int q1 = ((ph.x & 0x0F) << 4) + pl.y - 144; if (q1 < -128) q1 = -128;             \
        int q2 = (ph.y & 0xF0)        + pl.z - 144; if (q2 < -128) q2 = -128;             \
        int q3 = ((ph.y & 0x0F) << 4) + pl.w - 144; if (q3 < -128) q3 = -128;             \
        int packed = (q0 & 255) | ((q1 & 255) << 8) | ((q2 & 255) << 16) | ((q3 & 255) << 24); \
        *(int*)&Blds[(T) & 1][si >> 4][so][si & 12] = packed;                             \
        /* lgkmcnt(0) drains this thread's ds_write AND its tile-(T-1) ds_reads,  */      \
        /* so buf[(T)&1] is safe to rewrite at T+2; vmcnt NOT drained (prefetch). */      \
        asm volatile("s_waitcnt lgkmcnt(0)" ::: "memory");                                \
        __builtin_amdgcn_s_barrier();                                                     \
        v4i b0 = *(const v4i*)&Blds[(T) & 1][lane >> 4][lane & 15][0];                    \
        v4i b1 = *(const v4i*)&Blds[(T) & 1][lane >> 4][16 + (lane & 15)][0];             \
        acc00 = __builtin_amdgcn_mfma_i32_16x16x64_i8(a0, b0, acc00, 0, 0, 0);            \
        acc01 = __builtin_amdgcn_mfma_i32_16x16x64_i8(a0, b1, acc01, 0, 0, 0);            \
        acc10 = __builtin_amdgcn_mfma_i32_16x16x64_i8(a1, b0, acc10, 0, 0, 0);            \
        acc11 = __builtin_amdgcn_mfma_i32_16x16x64_i8(a1, b1, acc11, 0, 0, 0);            \
    }

    for (int t = 0; t < 127; ++t) {
        const int koff = (t + 1) << 6;
        // prefetch next tile (HBM latency hidden across this iteration)
        int4 pl_n = *(const int4*)(pl_ptr + koff);
        int2 ph_n = *(const int2*)(ph_ptr + (koff >> 1));
        v4i  a0_n = *(const v4i*)(a_ptr + koff);
        v4i  a1_n = *(const v4i*)(a_ptr + 16 * INF + koff);
        PROCESS_TILE(t);
        pl = pl_n; ph = ph_n; a0 = a0_n; a1 = a1_n;
    }
    PROCESS_TILE(127);
#undef PROCESS_TILE

    // --- epilogue: D[row][col] with col=lane&15, row=(lane>>4)*4+reg ---
    const float as  = act_scale[0];
    const int col   = lane & 15;
    const int rbase = (w << 5) + ((lane >> 4) << 2);

#define EPILOGUE(ACC, MI, CI)                                                  \
    {                                                                          \
        const int o   = n0 + (CI) * 16 + col;                                  \
        const float sc = as * scale[o];                                        \
        const float zo = zero_point[o];                                        \
        const float bo = bias[o];                                              \
        _Pragma("unroll")                                                      \
        for (int r = 0; r < 4; ++r) {                                          \
            const int trow = rbase + (MI) * 16 + r;                            \
            const float f = (float)ACC[r] - zo * (float)rowsum[trow];          \
            out[(size_t)trow * OUTF + o] = sc * f + bo;                        \
        }                                                                      \
    }
    EPILOGUE(acc00, 0, 0)
    EPILOGUE(acc01, 0, 1)
    EPILOGUE(acc10, 1, 0)
    EPILOGUE(acc11, 1, 1)
#undef EPILOGUE
}

extern "C" void kernel_launch(void* const* d_in, const int* in_sizes, int n_in,
                              void* d_out, int out_size, void* d_ws, size_t ws_size,
                              hipStream_t stream)
{
    const float* x           = (const float*)d_in[0];
    const int*   packed_high = (const int*)d_in[1];
    const int*   packed_low  = (const int*)d_in[2];
    const float* scale       = (const float*)d_in[3];
    const float* zero_point  = (const float*)d_in[4];
    const float* bias        = (const float*)d_in[5];
    const float* act_scale   = (const float*)d_in[6];
    float* out = (float*)d_out;

    signed char* xi8 = (signed char*)d_ws;
    int* rowsum = (int*)((char*)d_ws + (size_t)TOKENS * INF);

    quant_x_kernel<<<TOKENS, 256, 0, stream>>>(x, act_scale, xi8, rowsum);
    gemm_kernel<<<OUTF / 32, 512, 0, stream>>>(xi8, rowsum, packed_high, packed_low,
                                               scale, zero_point, bias, act_scale, out);
}